// Round 12
// baseline (1893.021 us; speedup 1.0000x reference)
//
#include <hip/hip_runtime.h>
#include <hip/hip_bf16.h>

#define V_SZ 100000
#define E_SZ 128
#define H_SZ 512
#define L_SZ 9
#define B_SZ 64
#define T_SZ 512
#define G4   (4*H_SZ)

#define LOGITS_N (B_SZ*T_SZ*L_SZ)            // 294912
#define HS_BYTES ((size_t)B_SZ*T_SZ*H_SZ*2)  // 33554432
#define SENT32 0x7FC07FC0u
#define SENT64 0x7FC07FC07FC07FC0ull

typedef short bf16x8 __attribute__((ext_vector_type(8)));
typedef float f32x4  __attribute__((ext_vector_type(4)));

static __device__ __forceinline__ unsigned short f2bf(float x){
  unsigned int u = __builtin_bit_cast(unsigned int, x);
  unsigned int r = (u + 0x7fffu + ((u >> 16) & 1u)) >> 16;
  return (unsigned short)r;
}
static __device__ __forceinline__ float bf2f(unsigned short b){
  unsigned int u = ((unsigned int)b) << 16;
  return __builtin_bit_cast(float, u);
}
static __device__ __forceinline__ float sig_f(float x){
  return 1.f / (1.f + __expf(-x));
}
static __device__ __forceinline__ float tanh_f(float x){
  float a = fabsf(x);
  float e = __expf(-2.f * a);
  float t = (1.f - e) / (1.f + e);
  return copysignf(t, x);
}

// ---------------- reset hs to sentinel (graph replays don't re-poison) ------
__global__ void k_reset(unsigned long long* __restrict__ hs64){
  const long n = HS_BYTES / 8;
  for (long i = (long)blockIdx.x*256 + threadIdx.x; i < n; i += (long)gridDim.x*256)
    __hip_atomic_store(&hs64[i], SENT64, __ATOMIC_RELAXED, __HIP_MEMORY_SCOPE_AGENT);
}

// ---------------- lens ----------------
__global__ void k_lens(const int* __restrict__ text, float* __restrict__ out_lens){
  int b = blockIdx.x;
  int c = 0;
  for (int t = threadIdx.x; t < T_SZ; t += 256)
    c += (text[b*T_SZ + t] != 0);
  for (int off = 32; off; off >>= 1) c += __shfl_down(c, off, 64);
  __shared__ int sred[4];
  int w = threadIdx.x >> 6;
  if ((threadIdx.x & 63) == 0) sred[w] = c;
  __syncthreads();
  if (threadIdx.x == 0)
    out_lens[b] = (float)(sred[0] + sred[1] + sred[2] + sred[3]);
}

// ---------------- fused embed + xg + LSTM recurrence ----------------
// r11 structure (8 groups x 32 blocks, g = bid&7, permuted B-layout, parity-
// double-buffered LDS, raw barriers, relaxed-agent data-is-flag protocol),
// now with 4-PHASE CONSUME-AS-ARRIVE:
//   phase ph covers K-cols [128ph, 128ph+128) = producers [8ph, 8ph+8).
//   Each thread spins on ONE 8B chunk (coalesced; one atomic store per chunk
//   -> lo-dword sentinel check suffices), stages it, pre-issues its next-
//   phase load (hides under barrier+MFMA), raw-barriers, then MFMAs that
//   phase's 4 K-chunks (x-MFMAs folded into phase 0). The post-last-arrival
//   tail shrinks from 20 MFMAs to 4 + gates; early-phase MFMAs overlap
//   late producers' publishes.
__global__ __launch_bounds__(256, 1)
void k_lstm(const int* __restrict__ text, const float* __restrict__ embed,
            const float* __restrict__ Wx, const float* __restrict__ Wh,
            const float* __restrict__ bias, unsigned short* __restrict__ hs)
{
  const int g    = blockIdx.x & 7;     // group (intended XCD under round-robin)
  const int j    = blockIdx.x >> 3;    // 0..31 block-in-group
  const int n0   = j * 16;             // owned h-columns [n0, n0+16)
  const int tid  = threadIdx.x;
  const int w    = tid >> 6;           // wave id
  const int lane = tid & 63;
  const int q    = lane >> 4;
  const int l16  = lane & 15;
  const int gate = l16 & 3;            // B-col -> gate
  const int cq   = l16 >> 2;           // B-col -> col-in-wave 0..3

  __shared__ unsigned short h_lds[2][16*512];   // 2 x 16 KB, swizzled, rows 8-15 zero
  __shared__ unsigned short x_lds[2][16*128];   // 2 x 4 KB,  swizzled, rows 8-15 zero

  for (int i = tid; i < 2*16*512; i += 256) ((unsigned short*)h_lds)[i] = 0;
  for (int i = tid; i < 2*16*128; i += 256) ((unsigned short*)x_lds)[i] = 0;

  // ---- weight B-frags (permuted): W[(kk*32 + q*8 + jj)][gate*H + hcol] ----
  const int hcol = n0 + w*4 + cq;
  const int gcol = gate*H_SZ + hcol;
  bf16x8 Whf[16];
#pragma unroll
  for (int kk = 0; kk < 16; ++kk){
    bf16x8 v;
#pragma unroll
    for (int jj = 0; jj < 8; ++jj)
      v[jj] = (short)f2bf(Wh[(long)(kk*32 + q*8 + jj)*G4 + gcol]);
    Whf[kk] = v;
  }
  bf16x8 Wxf[4];
#pragma unroll
  for (int kk = 0; kk < 4; ++kk){
    bf16x8 v;
#pragma unroll
    for (int jj = 0; jj < 8; ++jj)
      v[jj] = (short)f2bf(Wx[(long)(kk*32 + q*8 + jj)*G4 + gcol]);
    Wxf[kk] = v;
  }
  const float biasv = bias[gcol];

  // c-state: rows q*4+rg of the wave's column cq (used for q<2);
  // redundant across the 4 gate-lanes of each column.
  float cs[4] = {0.f, 0.f, 0.f, 0.f};
  const bool isPub = (gate == 0) && (cq == 0) && (q < 2);

  unsigned short* ppub[4];
#pragma unroll
  for (int rg = 0; rg < 4; ++rg)
    ppub[rg] = hs + ((long)(g*8 + q*4 + rg)*T_SZ)*H_SZ + n0 + w*4;

  // poll mapping: thread -> (row hr, chunk col c0); phase ph chunk = 32ph + c0
  const int hr = tid >> 5;             // 0..7
  const int c0 = tid & 31;             // 0..31

  // x-staging mapping (same every step)
  const int xr = tid >> 5;             // 0..7 (batch row)
  const int c4 = (tid & 31) * 4;       // f32 column
  const int cb = c4 * 2;               // byte col in LDS row
  unsigned short* xdst[2];
#pragma unroll
  for (int pb = 0; pb < 2; ++pb)
    xdst[pb] = (unsigned short*)((char*)x_lds[pb] + xr*256 + (cb ^ (xr << 4)));
  const int* tokp = text + (g*8 + xr)*T_SZ;

  __syncthreads();   // zeros visible (outside the loop; full barrier ok)

  // stage x for t=0 into x_lds[0] (ordered by the in-loop barrier at t=0)
  {
    int tok = tokp[0];
    const float4 xv = *(const float4*)(embed + (long)tok*E_SZ + c4);
    unsigned short* pp = xdst[0];
    pp[0] = f2bf(xv.x); pp[1] = f2bf(xv.y); pp[2] = f2bf(xv.z); pp[3] = f2bf(xv.w);
  }

#define RAW_BARRIER() do{ \
    asm volatile("s_waitcnt lgkmcnt(0)" ::: "memory"); \
    __builtin_amdgcn_sched_barrier(0); \
    __builtin_amdgcn_s_barrier(); \
    __builtin_amdgcn_sched_barrier(0); } while(0)

  for (int t = 0; t < T_SZ; ++t){
    const int par = t & 1;

    // ---- issue x_{t+1} embed loads NOW (latency hides under the poll) ----
    float4 xv; const bool havex = (t + 1 < T_SZ);
    if (havex){
      int tok = tokp[t + 1];
      xv = *(const float4*)(embed + (long)tok*E_SZ + c4);
    }

    f32x4 acc0 = {biasv, biasv, biasv, biasv};
    f32x4 acc1 = {0.f, 0.f, 0.f, 0.f};

    if (t == 0){
      RAW_BARRIER();
#pragma unroll
      for (int kk = 0; kk < 4; ++kk){
        bf16x8 a = *(const bf16x8*)((const char*)x_lds[par] + l16*256 + ((kk*64 + q*16) ^ (l16 << 4)));
        if (kk & 1) acc1 = __builtin_amdgcn_mfma_f32_16x16x32_bf16(a, Wxf[kk], acc1, 0, 0, 0);
        else        acc0 = __builtin_amdgcn_mfma_f32_16x16x32_bf16(a, Wxf[kk], acc0, 0, 0, 0);
      }
    } else {
      // per-thread chunk base for time t-1 (u64 units; row stride T*H/4)
      const unsigned long long* hp8 = (const unsigned long long*)hs
          + ((long)(g*8 + hr)*T_SZ + (t-1))*(H_SZ/4) + c0;
      unsigned long long v = __hip_atomic_load(hp8, __ATOMIC_RELAXED,
                                               __HIP_MEMORY_SCOPE_AGENT);
#pragma unroll
      for (int ph = 0; ph < 4; ++ph){
        // ---- spin on OWN chunk (data is the flag; one store per chunk) ----
        int it = 0;
        while ((unsigned int)v == SENT32 && ++it < (1 << 22))
          v = __hip_atomic_load(hp8 + ph*32, __ATOMIC_RELAXED,
                                __HIP_MEMORY_SCOPE_AGENT);
        // ---- stage this phase's chunk ----
        {
          int k4 = ph*32 + c0;
          *(unsigned long long*)((char*)h_lds[par] + hr*1024 + ((k4*8) ^ (hr << 4))) = v;
        }
        // ---- pre-issue next phase's load (hides under barrier + MFMA) ----
        if (ph < 3)
          v = __hip_atomic_load(hp8 + (ph+1)*32, __ATOMIC_RELAXED,
                                __HIP_MEMORY_SCOPE_AGENT);
        RAW_BARRIER();
        // ---- MFMA this phase: 4 h K-chunks (+ x in phase 0) ----
        if (ph == 0){
#pragma unroll
          for (int kk = 0; kk < 4; ++kk){
            bf16x8 a = *(const bf16x8*)((const char*)x_lds[par] + l16*256 + ((kk*64 + q*16) ^ (l16 << 4)));
            if (kk & 1) acc1 = __builtin_amdgcn_mfma_f32_16x16x32_bf16(a, Wxf[kk], acc1, 0, 0, 0);
            else        acc0 = __builtin_amdgcn_mfma_f32_16x16x32_bf16(a, Wxf[kk], acc0, 0, 0, 0);
          }
        }
#pragma unroll
        for (int kz = 0; kz < 4; ++kz){
          int kk = ph*4 + kz;
          bf16x8 a = *(const bf16x8*)((const char*)h_lds[par] + l16*1024 + ((kk*64 + q*16) ^ (l16 << 4)));
          if (kk & 1) acc1 = __builtin_amdgcn_mfma_f32_16x16x32_bf16(a, Whf[kk], acc1, 0, 0, 0);
          else        acc0 = __builtin_amdgcn_mfma_f32_16x16x32_bf16(a, Whf[kk], acc0, 0, 0, 0);
        }
      }
    }

    // ---- gates via quad shuffles; c,h; publish 8B (data-is-flag) ----
    // C/D: col = l16 -> (gate, cq); row = q*4+rg. xor-k neighbor holds gate^k.
#pragma unroll
    for (int rg = 0; rg < 4; ++rg){
      float v  = acc0[rg] + acc1[rg];
      float x1 = __shfl_xor(v, 1, 64);
      float x2 = __shfl_xor(v, 2, 64);
      float x3 = __shfl_xor(v, 3, 64);
      float gi = (gate==0)? v : (gate==1)? x1 : (gate==2)? x2 : x3;
      float gf = (gate==1)? v : (gate==0)? x1 : (gate==3)? x2 : x3;
      float gc = (gate==2)? v : (gate==3)? x1 : (gate==0)? x2 : x3;
      float go = (gate==3)? v : (gate==2)? x1 : (gate==1)? x2 : x3;
      cs[rg] = sig_f(gf)*cs[rg] + sig_f(gi)*tanh_f(gc);
      float hv = sig_f(go)*tanh_f(cs[rg]);
      unsigned int hb = (unsigned int)f2bf(hv);
      unsigned int pr  = (unsigned int)__shfl_xor((int)hb, 4, 64);   // col cq^1
      unsigned int pk  = hb | (pr << 16);                            // 2 cols
      unsigned int pk2 = (unsigned int)__shfl_xor((int)pk, 8, 64);   // cols cq^2
      unsigned long long p8 = (unsigned long long)pk
                            | ((unsigned long long)pk2 << 32);       // 4 cols
      if (isPub)
        __hip_atomic_store((unsigned long long*)ppub[rg], p8,
                           __ATOMIC_RELAXED, __HIP_MEMORY_SCOPE_AGENT);
    }
#pragma unroll
    for (int rg = 0; rg < 4; ++rg) ppub[rg] += H_SZ;

    // ---- write the prefetched x_{t+1} into the other parity buffer ----
    if (havex){
      unsigned short* pp = xdst[par ^ 1];
      pp[0] = f2bf(xv.x); pp[1] = f2bf(xv.y); pp[2] = f2bf(xv.z); pp[3] = f2bf(xv.w);
    }
    // no trailing barrier: next iteration uses the OTHER parity buffers
  }
#undef RAW_BARRIER
}

// ---------------- logits = hs @ Wd + bd ----------------
__global__ void k_logits(const unsigned short* __restrict__ hs,
                         const float* __restrict__ Wd, const float* __restrict__ bd,
                         float* __restrict__ out)
{
  __shared__ float wd_s[H_SZ*L_SZ];
  __shared__ float bd_s[L_SZ];
  for (int i = threadIdx.x; i < H_SZ*L_SZ; i += 128) wd_s[i] = Wd[i];
  if (threadIdx.x < L_SZ) bd_s[threadIdx.x] = bd[threadIdx.x];
  __syncthreads();

  long row = (long)blockIdx.x*128 + threadIdx.x;   // 0..32767
  const unsigned short* hp = hs + row*H_SZ;
  float acc[9];
#pragma unroll
  for (int jj = 0; jj < 9; ++jj) acc[jj] = 0.f;
  for (int k = 0; k < H_SZ; k += 8){
    uint4 v = *(const uint4*)(hp + k);
    const unsigned short* u = (const unsigned short*)&v;
#pragma unroll
    for (int l = 0; l < 8; ++l){
      float hf = bf2f(u[l]);
#pragma unroll
      for (int jj = 0; jj < 9; ++jj)
        acc[jj] = fmaf(hf, wd_s[(k + l)*L_SZ + jj], acc[jj]);
    }
  }
  float* op = out + row*L_SZ;
#pragma unroll
  for (int jj = 0; jj < 9; ++jj) op[jj] = acc[jj] + bd_s[jj];
}

// ---------------- CRF: score + forward algorithm ----------------
__global__ void k_crf(const float* __restrict__ logits, const int* __restrict__ labels,
                      const float* __restrict__ trans, const float* __restrict__ lensf,
                      float* __restrict__ out_ll)
{
  int b = blockIdx.x;
  int lane = threadIdx.x;             // 64 threads = 1 wave
  int len = (int)lensf[b];
  const float* lg  = logits + (long)b*T_SZ*L_SZ;
  const int*   lab = labels + b*T_SZ;

  float s = 0.f;
  for (int t = lane; t < T_SZ; t += 64){
    if (t < len){
      s += lg[t*L_SZ + lab[t]];
      if (t >= 1) s += trans[lab[t-1]*L_SZ + lab[t]];
    }
  }
  for (int off = 32; off; off >>= 1) s += __shfl_down(s, off, 64);

  float tr[9];
#pragma unroll
  for (int i = 0; i < 9; ++i) tr[i] = (lane < 9) ? trans[i*L_SZ + lane] : 0.f;
  float alpha = (lane < 9) ? lg[lane] : -1e30f;

  for (int t = 1; t < T_SZ; ++t){
    float tmp[9];
#pragma unroll
    for (int i = 0; i < 9; ++i){
      float ai = __shfl(alpha, i, 64);
      tmp[i] = ai + tr[i];
    }
    float m0 = fmaxf(fmaxf(tmp[0], tmp[1]), tmp[2]);
    float m1 = fmaxf(fmaxf(tmp[3], tmp[4]), tmp[5]);
    float m2 = fmaxf(fmaxf(tmp[6], tmp[7]), tmp[8]);
    float m  = fmaxf(fmaxf(m0, m1), m2);
    float e = 0.f;
#pragma unroll
    for (int i = 0; i < 9; ++i) e += __expf(tmp[i] - m);
    float lgv = (lane < 9) ? lg[t*L_SZ + lane] : 0.f;
    float nv = m + __logf(e) + lgv;
    if (t < len && lane < 9) alpha = nv;
  }

  float mm = (lane < 9) ? alpha : -1e30f;
  for (int off = 8; off; off >>= 1) mm = fmaxf(mm, __shfl_down(mm, off, 64));
  mm = __shfl(mm, 0, 64);
  float ee = (lane < 9) ? __expf(alpha - mm) : 0.f;
  for (int off = 8; off; off >>= 1) ee += __shfl_down(ee, off, 64);
  if (lane == 0) out_ll[b] = s - (mm + __logf(ee));
}

extern "C" void kernel_launch(void* const* d_in, const int* in_sizes, int n_in,
                              void* d_out, int out_size, void* d_ws, size_t ws_size,
                              hipStream_t stream)
{
  const int*   text   = (const int*)  d_in[0];
  const int*   labels = (const int*)  d_in[1];
  const float* embed  = (const float*)d_in[2];
  const float* Wx     = (const float*)d_in[3];
  const float* Wh     = (const float*)d_in[4];
  const float* bias   = (const float*)d_in[5];
  const float* Wd     = (const float*)d_in[6];
  const float* bd     = (const float*)d_in[7];
  const float* trans  = (const float*)d_in[8];

  float* out        = (float*)d_out;
  float* out_logits = out;
  float* out_lens   = out + LOGITS_N;
  float* out_ll     = out + LOGITS_N + B_SZ;

  unsigned short* hs = (unsigned short*)d_ws;

  k_reset <<<2048, 256, 0, stream>>>((unsigned long long*)hs);
  k_lens  <<<B_SZ, 256, 0, stream>>>(text, out_lens);
  k_lstm  <<<256, 256, 0, stream>>>(text, embed, Wx, Wh, bias, hs);
  k_logits<<<256, 128, 0, stream>>>(hs, Wd, bd, out_logits);
  k_crf   <<<B_SZ, 64, 0, stream>>>(out_logits, labels, trans, out_lens, out_ll);
}

// Round 13
// 1817.031 us; speedup vs baseline: 1.0418x; 1.0418x over previous
//
#include <hip/hip_runtime.h>
#include <hip/hip_bf16.h>

#define V_SZ 100000
#define E_SZ 128
#define H_SZ 512
#define L_SZ 9
#define B_SZ 64
#define T_SZ 512
#define G4   (4*H_SZ)

#define LOGITS_N (B_SZ*T_SZ*L_SZ)            // 294912
#define HS_BYTES ((size_t)B_SZ*T_SZ*H_SZ*2)  // 33554432
#define SENT32 0x7FC07FC0u
#define SENT64 0x7FC07FC07FC07FC0ull

typedef short bf16x8 __attribute__((ext_vector_type(8)));
typedef float f32x4  __attribute__((ext_vector_type(4)));

static __device__ __forceinline__ unsigned short f2bf(float x){
  unsigned int u = __builtin_bit_cast(unsigned int, x);
  unsigned int r = (u + 0x7fffu + ((u >> 16) & 1u)) >> 16;
  return (unsigned short)r;
}
static __device__ __forceinline__ float bf2f(unsigned short b){
  unsigned int u = ((unsigned int)b) << 16;
  return __builtin_bit_cast(float, u);
}
static __device__ __forceinline__ float sig_f(float x){
  return 1.f / (1.f + __expf(-x));
}
static __device__ __forceinline__ float tanh_f(float x){
  float a = fabsf(x);
  float e = __expf(-2.f * a);
  float t = (1.f - e) / (1.f + e);
  return copysignf(t, x);
}

// ---------------- reset hs to sentinel (graph replays don't re-poison) ------
__global__ void k_reset(unsigned long long* __restrict__ hs64){
  const long n = HS_BYTES / 8;
  for (long i = (long)blockIdx.x*256 + threadIdx.x; i < n; i += (long)gridDim.x*256)
    __hip_atomic_store(&hs64[i], SENT64, __ATOMIC_RELAXED, __HIP_MEMORY_SCOPE_AGENT);
}

// ---------------- lens ----------------
__global__ void k_lens(const int* __restrict__ text, float* __restrict__ out_lens){
  int b = blockIdx.x;
  int c = 0;
  for (int t = threadIdx.x; t < T_SZ; t += 256)
    c += (text[b*T_SZ + t] != 0);
  for (int off = 32; off; off >>= 1) c += __shfl_down(c, off, 64);
  __shared__ int sred[4];
  int w = threadIdx.x >> 6;
  if ((threadIdx.x & 63) == 0) sred[w] = c;
  __syncthreads();
  if (threadIdx.x == 0)
    out_lens[b] = (float)(sred[0] + sred[1] + sred[2] + sred[3]);
}

// ---------------- fused embed + xg + LSTM recurrence ----------------
// r11 schedule with HALVED PRODUCER COUNT: 8 groups x 16 blocks x 512 threads
// (8 waves). Wave w keeps r7's exact proven per-wave shape — owns 4 h-cols
// (n0 + 4w + cq, permuted B-layout gate = l16&3), 20 MFMAs, same gate
// shuffles and 8B publishes — so per-wave serial work is unchanged while
// group skew is max-over-16 (was 32) and each block's 8 waves publish one
// full 64B line per row. Poll: per-thread independent 2-chunk spin (exit the
// moment OWN chunks arrive; iteration = 2-load RT), then one lgkm-only raw
// barrier. Parity-double-buffered LDS; x_{t+1} issued at step top.
// Coherence ops identical to r6-r11: relaxed agent 8B atomics, data-is-flag.
__global__ __launch_bounds__(512, 1)
void k_lstm(const int* __restrict__ text, const float* __restrict__ embed,
            const float* __restrict__ Wx, const float* __restrict__ Wh,
            const float* __restrict__ bias, unsigned short* __restrict__ hs)
{
  const int g    = blockIdx.x & 7;     // group (intended XCD under round-robin)
  const int j    = blockIdx.x >> 3;    // 0..15 block-in-group
  const int n0   = j * 32;             // owned h-columns [n0, n0+32)
  const int tid  = threadIdx.x;        // 0..511
  const int w    = tid >> 6;           // wave id 0..7
  const int lane = tid & 63;
  const int q    = lane >> 4;
  const int l16  = lane & 15;
  const int gate = l16 & 3;            // B-col -> gate
  const int cq   = l16 >> 2;           // B-col -> col-in-wave 0..3

  __shared__ unsigned short h_lds[2][16*512];   // 2 x 16 KB, swizzled, rows 8-15 zero
  __shared__ unsigned short x_lds[2][16*128];   // 2 x 4 KB,  swizzled, rows 8-15 zero

  for (int i = tid; i < 2*16*512; i += 512) ((unsigned short*)h_lds)[i] = 0;
  for (int i = tid; i < 2*16*128; i += 512) ((unsigned short*)x_lds)[i] = 0;

  // ---- weight B-frags (permuted): W[(kk*32 + q*8 + jj)][gate*H + hcol] ----
  const int hcol = n0 + w*4 + cq;
  const int gcol = gate*H_SZ + hcol;
  bf16x8 Whf[16];
#pragma unroll
  for (int kk = 0; kk < 16; ++kk){
    bf16x8 v;
#pragma unroll
    for (int jj = 0; jj < 8; ++jj)
      v[jj] = (short)f2bf(Wh[(long)(kk*32 + q*8 + jj)*G4 + gcol]);
    Whf[kk] = v;
  }
  bf16x8 Wxf[4];
#pragma unroll
  for (int kk = 0; kk < 4; ++kk){
    bf16x8 v;
#pragma unroll
    for (int jj = 0; jj < 8; ++jj)
      v[jj] = (short)f2bf(Wx[(long)(kk*32 + q*8 + jj)*G4 + gcol]);
    Wxf[kk] = v;
  }
  const float biasv = bias[gcol];

  // c-state: rows q*4+rg of the wave's column cq (used for q<2);
  // redundant across the 4 gate-lanes of each column.
  float cs[4] = {0.f, 0.f, 0.f, 0.f};
  const bool isPub = (gate == 0) && (cq == 0) && (q < 2);

  unsigned short* ppub[4];
#pragma unroll
  for (int rg = 0; rg < 4; ++rg)
    ppub[rg] = hs + ((long)(g*8 + q*4 + rg)*T_SZ)*H_SZ + n0 + w*4;

  // poll mapping: 1024 chunks (8 rows x 128), thread owns chunks tid, tid+512
  const int hr0 = tid >> 7;            // 0..3   (chunk tid)
  const int k40 = tid & 127;
  const int hr1 = hr0 + 4;             // 4..7   (chunk tid+512)
  const int k41 = k40;

  // x-staging mapping: row xr (0..7), f32 cols [c2, c2+2)
  const int xr = tid >> 6;             // 0..7
  const int c2 = (tid & 63) * 2;       // f32 col
  const int cb = c2 * 2;               // byte col in LDS row
  unsigned short* xdst[2];
#pragma unroll
  for (int pb = 0; pb < 2; ++pb)
    xdst[pb] = (unsigned short*)((char*)x_lds[pb] + xr*256 + (cb ^ (xr << 4)));
  const int* tokp = text + (g*8 + xr)*T_SZ;

  __syncthreads();   // zeros visible (outside the loop; full barrier ok)

  // stage x for t=0 into x_lds[0] (ordered by the in-loop barrier at t=0)
  {
    int tok = tokp[0];
    const float2 xv = *(const float2*)(embed + (long)tok*E_SZ + c2);
    unsigned short* pp = xdst[0];
    pp[0] = f2bf(xv.x); pp[1] = f2bf(xv.y);
  }

  for (int t = 0; t < T_SZ; ++t){
    const int par = t & 1;

    // ---- issue x_{t+1} embed loads NOW (latency hides under the poll) ----
    float2 xv; const bool havex = (t + 1 < T_SZ);
    if (havex){
      int tok = tokp[t + 1];
      xv = *(const float2*)(embed + (long)tok*E_SZ + c2);
    }

    if (t > 0){
      // ---- per-thread independent spin on OWN 2 chunks (data is the flag) ----
      const unsigned long long* p0 = (const unsigned long long*)
          (hs + ((long)(g*8 + hr0)*T_SZ + (t-1))*H_SZ + k40*4);
      const unsigned long long* p1 = (const unsigned long long*)
          (hs + ((long)(g*8 + hr1)*T_SZ + (t-1))*H_SZ + k41*4);
      unsigned long long v0 = __hip_atomic_load(p0, __ATOMIC_RELAXED,
                                                __HIP_MEMORY_SCOPE_AGENT);
      unsigned long long v1 = __hip_atomic_load(p1, __ATOMIC_RELAXED,
                                                __HIP_MEMORY_SCOPE_AGENT);
      int it = 0;
      while ((((unsigned int)v0 == SENT32) | ((unsigned int)v1 == SENT32))
             && ++it < (1 << 21)){
        if ((unsigned int)v0 == SENT32)
          v0 = __hip_atomic_load(p0, __ATOMIC_RELAXED, __HIP_MEMORY_SCOPE_AGENT);
        if ((unsigned int)v1 == SENT32)
          v1 = __hip_atomic_load(p1, __ATOMIC_RELAXED, __HIP_MEMORY_SCOPE_AGENT);
      }
      *(unsigned long long*)((char*)h_lds[par] + hr0*1024 + ((k40*8) ^ (hr0 << 4))) = v0;
      *(unsigned long long*)((char*)h_lds[par] + hr1*1024 + ((k41*8) ^ (hr1 << 4))) = v1;
    }

    // ---- raw barrier: order LDS only (no vmcnt drain -> publish acks and
    //      in-flight embed loads stay off the critical path) ----
    asm volatile("s_waitcnt lgkmcnt(0)" ::: "memory");
    __builtin_amdgcn_sched_barrier(0);
    __builtin_amdgcn_s_barrier();
    __builtin_amdgcn_sched_barrier(0);

    // ---- MFMA: gates = x_t @ Wx (+ h_{t-1} @ Wh) + b ----
    f32x4 acc0 = {biasv, biasv, biasv, biasv};
    f32x4 acc1 = {0.f, 0.f, 0.f, 0.f};
#pragma unroll
    for (int kk = 0; kk < 4; ++kk){
      bf16x8 a = *(const bf16x8*)((const char*)x_lds[par] + l16*256 + ((kk*64 + q*16) ^ (l16 << 4)));
      if (kk & 1) acc1 = __builtin_amdgcn_mfma_f32_16x16x32_bf16(a, Wxf[kk], acc1, 0, 0, 0);
      else        acc0 = __builtin_amdgcn_mfma_f32_16x16x32_bf16(a, Wxf[kk], acc0, 0, 0, 0);
    }
    if (t > 0){
#pragma unroll
      for (int kk = 0; kk < 16; ++kk){
        bf16x8 a = *(const bf16x8*)((const char*)h_lds[par] + l16*1024 + ((kk*64 + q*16) ^ (l16 << 4)));
        if (kk & 1) acc1 = __builtin_amdgcn_mfma_f32_16x16x32_bf16(a, Whf[kk], acc1, 0, 0, 0);
        else        acc0 = __builtin_amdgcn_mfma_f32_16x16x32_bf16(a, Whf[kk], acc0, 0, 0, 0);
      }
    }

    // ---- gates via quad shuffles; c,h; publish 8B (data-is-flag) ----
    // C/D: col = l16 -> (gate, cq); row = q*4+rg. xor-k neighbor holds gate^k.
#pragma unroll
    for (int rg = 0; rg < 4; ++rg){
      float v  = acc0[rg] + acc1[rg];
      float x1 = __shfl_xor(v, 1, 64);
      float x2 = __shfl_xor(v, 2, 64);
      float x3 = __shfl_xor(v, 3, 64);
      float gi = (gate==0)? v : (gate==1)? x1 : (gate==2)? x2 : x3;
      float gf = (gate==1)? v : (gate==0)? x1 : (gate==3)? x2 : x3;
      float gc = (gate==2)? v : (gate==3)? x1 : (gate==0)? x2 : x3;
      float go = (gate==3)? v : (gate==2)? x1 : (gate==1)? x2 : x3;
      cs[rg] = sig_f(gf)*cs[rg] + sig_f(gi)*tanh_f(gc);
      float hv = sig_f(go)*tanh_f(cs[rg]);
      unsigned int hb = (unsigned int)f2bf(hv);
      unsigned int pr  = (unsigned int)__shfl_xor((int)hb, 4, 64);   // col cq^1
      unsigned int pk  = hb | (pr << 16);                            // 2 cols
      unsigned int pk2 = (unsigned int)__shfl_xor((int)pk, 8, 64);   // cols cq^2
      unsigned long long p8 = (unsigned long long)pk
                            | ((unsigned long long)pk2 << 32);       // 4 cols
      if (isPub)
        __hip_atomic_store((unsigned long long*)ppub[rg], p8,
                           __ATOMIC_RELAXED, __HIP_MEMORY_SCOPE_AGENT);
    }
#pragma unroll
    for (int rg = 0; rg < 4; ++rg) ppub[rg] += H_SZ;

    // ---- write the prefetched x_{t+1} into the other parity buffer ----
    if (havex){
      unsigned short* pp = xdst[par ^ 1];
      pp[0] = f2bf(xv.x); pp[1] = f2bf(xv.y);
    }
    // no trailing barrier: next iteration uses the OTHER parity buffers
  }
}

// ---------------- logits = hs @ Wd + bd ----------------
__global__ void k_logits(const unsigned short* __restrict__ hs,
                         const float* __restrict__ Wd, const float* __restrict__ bd,
                         float* __restrict__ out)
{
  __shared__ float wd_s[H_SZ*L_SZ];
  __shared__ float bd_s[L_SZ];
  for (int i = threadIdx.x; i < H_SZ*L_SZ; i += 128) wd_s[i] = Wd[i];
  if (threadIdx.x < L_SZ) bd_s[threadIdx.x] = bd[threadIdx.x];
  __syncthreads();

  long row = (long)blockIdx.x*128 + threadIdx.x;   // 0..32767
  const unsigned short* hp = hs + row*H_SZ;
  float acc[9];
#pragma unroll
  for (int jj = 0; jj < 9; ++jj) acc[jj] = 0.f;
  for (int k = 0; k < H_SZ; k += 8){
    uint4 v = *(const uint4*)(hp + k);
    const unsigned short* u = (const unsigned short*)&v;
#pragma unroll
    for (int l = 0; l < 8; ++l){
      float hf = bf2f(u[l]);
#pragma unroll
      for (int jj = 0; jj < 9; ++jj)
        acc[jj] = fmaf(hf, wd_s[(k + l)*L_SZ + jj], acc[jj]);
    }
  }
  float* op = out + row*L_SZ;
#pragma unroll
  for (int jj = 0; jj < 9; ++jj) op[jj] = acc[jj] + bd_s[jj];
}

// ---------------- CRF: score + forward algorithm ----------------
__global__ void k_crf(const float* __restrict__ logits, const int* __restrict__ labels,
                      const float* __restrict__ trans, const float* __restrict__ lensf,
                      float* __restrict__ out_ll)
{
  int b = blockIdx.x;
  int lane = threadIdx.x;             // 64 threads = 1 wave
  int len = (int)lensf[b];
  const float* lg  = logits + (long)b*T_SZ*L_SZ;
  const int*   lab = labels + b*T_SZ;

  float s = 0.f;
  for (int t = lane; t < T_SZ; t += 64){
    if (t < len){
      s += lg[t*L_SZ + lab[t]];
      if (t >= 1) s += trans[lab[t-1]*L_SZ + lab[t]];
    }
  }
  for (int off = 32; off; off >>= 1) s += __shfl_down(s, off, 64);

  float tr[9];
#pragma unroll
  for (int i = 0; i < 9; ++i) tr[i] = (lane < 9) ? trans[i*L_SZ + lane] : 0.f;
  float alpha = (lane < 9) ? lg[lane] : -1e30f;

  for (int t = 1; t < T_SZ; ++t){
    float tmp[9];
#pragma unroll
    for (int i = 0; i < 9; ++i){
      float ai = __shfl(alpha, i, 64);
      tmp[i] = ai + tr[i];
    }
    float m0 = fmaxf(fmaxf(tmp[0], tmp[1]), tmp[2]);
    float m1 = fmaxf(fmaxf(tmp[3], tmp[4]), tmp[5]);
    float m2 = fmaxf(fmaxf(tmp[6], tmp[7]), tmp[8]);
    float m  = fmaxf(fmaxf(m0, m1), m2);
    float e = 0.f;
#pragma unroll
    for (int i = 0; i < 9; ++i) e += __expf(tmp[i] - m);
    float lgv = (lane < 9) ? lg[t*L_SZ + lane] : 0.f;
    float nv = m + __logf(e) + lgv;
    if (t < len && lane < 9) alpha = nv;
  }

  float mm = (lane < 9) ? alpha : -1e30f;
  for (int off = 8; off; off >>= 1) mm = fmaxf(mm, __shfl_down(mm, off, 64));
  mm = __shfl(mm, 0, 64);
  float ee = (lane < 9) ? __expf(alpha - mm) : 0.f;
  for (int off = 8; off; off >>= 1) ee += __shfl_down(ee, off, 64);
  if (lane == 0) out_ll[b] = s - (mm + __logf(ee));
}

extern "C" void kernel_launch(void* const* d_in, const int* in_sizes, int n_in,
                              void* d_out, int out_size, void* d_ws, size_t ws_size,
                              hipStream_t stream)
{
  const int*   text   = (const int*)  d_in[0];
  const int*   labels = (const int*)  d_in[1];
  const float* embed  = (const float*)d_in[2];
  const float* Wx     = (const float*)d_in[3];
  const float* Wh     = (const float*)d_in[4];
  const float* bias   = (const float*)d_in[5];
  const float* Wd     = (const float*)d_in[6];
  const float* bd     = (const float*)d_in[7];
  const float* trans  = (const float*)d_in[8];

  float* out        = (float*)d_out;
  float* out_logits = out;
  float* out_lens   = out + LOGITS_N;
  float* out_ll     = out + LOGITS_N + B_SZ;

  unsigned short* hs = (unsigned short*)d_ws;

  k_reset <<<2048, 256, 0, stream>>>((unsigned long long*)hs);
  k_lens  <<<B_SZ, 256, 0, stream>>>(text, out_lens);
  k_lstm  <<<128, 512, 0, stream>>>(text, embed, Wx, Wh, bias, hs);
  k_logits<<<256, 128, 0, stream>>>(hs, Wd, bd, out_logits);
  k_crf   <<<B_SZ, 64, 0, stream>>>(out_logits, labels, trans, out_lens, out_ll);
}

// Round 14
// 1551.707 us; speedup vs baseline: 1.2200x; 1.1710x over previous
//
#include <hip/hip_runtime.h>
#include <hip/hip_bf16.h>

#define V_SZ 100000
#define E_SZ 128
#define H_SZ 512
#define L_SZ 9
#define B_SZ 64
#define T_SZ 512
#define G4   (4*H_SZ)

#define LOGITS_N (B_SZ*T_SZ*L_SZ)            // 294912
#define HS_BYTES ((size_t)B_SZ*T_SZ*H_SZ*2)  // 33554432
#define SENT32 0x7FC07FC0u
#define SENT64 0x7FC07FC07FC07FC0ull

typedef short bf16x8 __attribute__((ext_vector_type(8)));
typedef float f32x4  __attribute__((ext_vector_type(4)));

static __device__ __forceinline__ unsigned short f2bf(float x){
  unsigned int u = __builtin_bit_cast(unsigned int, x);
  unsigned int r = (u + 0x7fffu + ((u >> 16) & 1u)) >> 16;
  return (unsigned short)r;
}
static __device__ __forceinline__ float bf2f(unsigned short b){
  unsigned int u = ((unsigned int)b) << 16;
  return __builtin_bit_cast(float, u);
}
static __device__ __forceinline__ float sig_f(float x){
  return 1.f / (1.f + __expf(-x));
}
static __device__ __forceinline__ float tanh_f(float x){
  float a = fabsf(x);
  float e = __expf(-2.f * a);
  float t = (1.f - e) / (1.f + e);
  return copysignf(t, x);
}

// ---------------- reset hs to sentinel (graph replays don't re-poison) ------
__global__ void k_reset(unsigned long long* __restrict__ hs64){
  const long n = HS_BYTES / 8;
  for (long i = (long)blockIdx.x*256 + threadIdx.x; i < n; i += (long)gridDim.x*256)
    __hip_atomic_store(&hs64[i], SENT64, __ATOMIC_RELAXED, __HIP_MEMORY_SCOPE_AGENT);
}

// ---------------- lens ----------------
__global__ void k_lens(const int* __restrict__ text, float* __restrict__ out_lens){
  int b = blockIdx.x;
  int c = 0;
  for (int t = threadIdx.x; t < T_SZ; t += 256)
    c += (text[b*T_SZ + t] != 0);
  for (int off = 32; off; off >>= 1) c += __shfl_down(c, off, 64);
  __shared__ int sred[4];
  int w = threadIdx.x >> 6;
  if ((threadIdx.x & 63) == 0) sred[w] = c;
  __syncthreads();
  if (threadIdx.x == 0)
    out_lens[b] = (float)(sred[0] + sred[1] + sred[2] + sred[3]);
}

// ---------------- fused embed + xg + LSTM recurrence ----------------
// r11's proven structure (8 groups x 32 blocks, g = bid&7 XCD-local, permuted
// B-layout, coalesced all-chunk poll, raw lgkm-only barrier, one barrier per
// step, relaxed-agent data-is-flag protocol), plus two tail/quantum cuts:
//  (1) x staged TWO steps ahead into 3 rotating LDS buffers, so the 4 x-MFMAs
//      (+ acc init) run BEFORE the poll, inside the spin window. Writes at
//      end of step t to buf[(t+2)%3] are separated from their pre-barrier
//      reads at step t+2 by barrier(t+1), and from the previous reader
//      (pre-barrier at t-1) by barrier(t)-ordering. Race-free.
//  (2) lo-dword-only sentinel check (each 8B chunk = exactly one 8B atomic
//      store) -> half the compares per poll iteration.
__global__ __launch_bounds__(256, 1)
void k_lstm(const int* __restrict__ text, const float* __restrict__ embed,
            const float* __restrict__ Wx, const float* __restrict__ Wh,
            const float* __restrict__ bias, unsigned short* __restrict__ hs)
{
  const int g    = blockIdx.x & 7;     // group (intended XCD under round-robin)
  const int j    = blockIdx.x >> 3;    // 0..31 block-in-group
  const int n0   = j * 16;             // owned h-columns [n0, n0+16)
  const int tid  = threadIdx.x;
  const int w    = tid >> 6;           // wave id
  const int lane = tid & 63;
  const int q    = lane >> 4;
  const int l16  = lane & 15;
  const int gate = l16 & 3;            // B-col -> gate
  const int cq   = l16 >> 2;           // B-col -> col-in-wave 0..3

  __shared__ unsigned short h_lds[2][16*512];   // 2 x 16 KB, swizzled, rows 8-15 zero
  __shared__ unsigned short x_lds[3][16*128];   // 3 x 4 KB,  swizzled, rows 8-15 zero

  for (int i = tid; i < 2*16*512; i += 256) ((unsigned short*)h_lds)[i] = 0;
  for (int i = tid; i < 3*16*128; i += 256) ((unsigned short*)x_lds)[i] = 0;

  // ---- weight B-frags (permuted): W[(kk*32 + q*8 + jj)][gate*H + hcol] ----
  const int hcol = n0 + w*4 + cq;
  const int gcol = gate*H_SZ + hcol;
  bf16x8 Whf[16];
#pragma unroll
  for (int kk = 0; kk < 16; ++kk){
    bf16x8 v;
#pragma unroll
    for (int jj = 0; jj < 8; ++jj)
      v[jj] = (short)f2bf(Wh[(long)(kk*32 + q*8 + jj)*G4 + gcol]);
    Whf[kk] = v;
  }
  bf16x8 Wxf[4];
#pragma unroll
  for (int kk = 0; kk < 4; ++kk){
    bf16x8 v;
#pragma unroll
    for (int jj = 0; jj < 8; ++jj)
      v[jj] = (short)f2bf(Wx[(long)(kk*32 + q*8 + jj)*G4 + gcol]);
    Wxf[kk] = v;
  }
  const float biasv = bias[gcol];

  // c-state: rows q*4+rg of the wave's column cq (used for q<2);
  // redundant across the 4 gate-lanes of each column.
  float cs[4] = {0.f, 0.f, 0.f, 0.f};
  const bool isPub = (gate == 0) && (cq == 0) && (q < 2);

  unsigned short* ppub[4];
#pragma unroll
  for (int rg = 0; rg < 4; ++rg)
    ppub[rg] = hs + ((long)(g*8 + q*4 + rg)*T_SZ)*H_SZ + n0 + w*4;

  // x-staging mapping (same every step)
  const int xr = tid >> 5;             // 0..7 (batch row)
  const int c4 = (tid & 31) * 4;       // f32 column
  const int cb = c4 * 2;               // byte col in LDS row
  unsigned short* xdst[3];
#pragma unroll
  for (int pb = 0; pb < 3; ++pb)
    xdst[pb] = (unsigned short*)((char*)x_lds[pb] + xr*256 + (cb ^ (xr << 4)));
  const int* tokp = text + (g*8 + xr)*T_SZ;

  __syncthreads();   // zeros visible

  // prologue: stage x for t=0 (buf 0) and t=1 (buf 1)
#pragma unroll
  for (int tt = 0; tt < 2; ++tt){
    int tok = tokp[tt];
    const float4 xv = *(const float4*)(embed + (long)tok*E_SZ + c4);
    unsigned short* pp = xdst[tt];
    pp[0] = f2bf(xv.x); pp[1] = f2bf(xv.y); pp[2] = f2bf(xv.z); pp[3] = f2bf(xv.w);
  }
  __syncthreads();   // prologue x staging visible to all waves

  for (int t = 0; t < T_SZ; ++t){
    const int par = t & 1;
    const int xb  = t % 3;

    // ---- issue x_{t+2} embed loads NOW (latency hides under the poll) ----
    float4 xv; const bool havex = (t + 2 < T_SZ);
    if (havex){
      int tok = tokp[t + 2];
      xv = *(const float4*)(embed + (long)tok*E_SZ + c4);
    }

    // ---- x-MFMAs BEFORE the poll (x_lds[xb] written >= 2 steps ago,
    //      ordered by barrier(t-1); runs inside the spin window) ----
    f32x4 acc0 = {biasv, biasv, biasv, biasv};
    f32x4 acc1 = {0.f, 0.f, 0.f, 0.f};
#pragma unroll
    for (int kk = 0; kk < 4; ++kk){
      bf16x8 a = *(const bf16x8*)((const char*)x_lds[xb] + l16*256 + ((kk*64 + q*16) ^ (l16 << 4)));
      if (kk & 1) acc1 = __builtin_amdgcn_mfma_f32_16x16x32_bf16(a, Wxf[kk], acc1, 0, 0, 0);
      else        acc0 = __builtin_amdgcn_mfma_f32_16x16x32_bf16(a, Wxf[kk], acc0, 0, 0, 0);
    }

    if (t > 0){
      // ---- poll h_{t-1} (data is the flag), then stage to LDS ----
      unsigned long long v[4];
      int it = 0; bool ok;
      do {
        ok = true;
#pragma unroll
        for (int c = 0; c < 4; ++c){
          int chunk = tid + 256*c;            // 0..1023
          int hr    = chunk >> 7;             // 0..7
          int k4    = chunk & 127;            // 8B chunk -> cols k4*4
          v[c] = __hip_atomic_load(
              (const unsigned long long*)(hs + ((long)(g*8 + hr)*T_SZ + (t-1))*H_SZ + k4*4),
              __ATOMIC_RELAXED, __HIP_MEMORY_SCOPE_AGENT);
        }
#pragma unroll
        for (int c = 0; c < 4; ++c)
          ok = ok && ((unsigned int)v[c] != SENT32);   // 1 store per 8B chunk
      } while (!ok && ++it < (1 << 20));
#pragma unroll
      for (int c = 0; c < 4; ++c){
        int chunk = tid + 256*c;
        int hr    = chunk >> 7;
        int k4    = chunk & 127;
        *(unsigned long long*)((char*)h_lds[par] + hr*1024 + ((k4*8) ^ (hr << 4))) = v[c];
      }
    }

    // ---- raw barrier: order LDS only (no vmcnt drain -> publish acks and
    //      in-flight embed loads stay off the critical path) ----
    asm volatile("s_waitcnt lgkmcnt(0)" ::: "memory");
    __builtin_amdgcn_sched_barrier(0);
    __builtin_amdgcn_s_barrier();
    __builtin_amdgcn_sched_barrier(0);

    // ---- h-MFMAs (the only post-arrival compute besides gates) ----
    if (t > 0){
#pragma unroll
      for (int kk = 0; kk < 16; ++kk){
        bf16x8 a = *(const bf16x8*)((const char*)h_lds[par] + l16*1024 + ((kk*64 + q*16) ^ (l16 << 4)));
        if (kk & 1) acc1 = __builtin_amdgcn_mfma_f32_16x16x32_bf16(a, Whf[kk], acc1, 0, 0, 0);
        else        acc0 = __builtin_amdgcn_mfma_f32_16x16x32_bf16(a, Whf[kk], acc0, 0, 0, 0);
      }
    }

    // ---- gates via quad shuffles; c,h; publish 8B (data-is-flag) ----
    // C/D: col = l16 -> (gate, cq); row = q*4+rg. xor-k neighbor holds gate^k.
#pragma unroll
    for (int rg = 0; rg < 4; ++rg){
      float v  = acc0[rg] + acc1[rg];
      float x1 = __shfl_xor(v, 1, 64);
      float x2 = __shfl_xor(v, 2, 64);
      float x3 = __shfl_xor(v, 3, 64);
      float gi = (gate==0)? v : (gate==1)? x1 : (gate==2)? x2 : x3;
      float gf = (gate==1)? v : (gate==0)? x1 : (gate==3)? x2 : x3;
      float gc = (gate==2)? v : (gate==3)? x1 : (gate==0)? x2 : x3;
      float go = (gate==3)? v : (gate==2)? x1 : (gate==1)? x2 : x3;
      cs[rg] = sig_f(gf)*cs[rg] + sig_f(gi)*tanh_f(gc);
      float hv = sig_f(go)*tanh_f(cs[rg]);
      unsigned int hb = (unsigned int)f2bf(hv);
      unsigned int pr  = (unsigned int)__shfl_xor((int)hb, 4, 64);   // col cq^1
      unsigned int pk  = hb | (pr << 16);                            // 2 cols
      unsigned int pk2 = (unsigned int)__shfl_xor((int)pk, 8, 64);   // cols cq^2
      unsigned long long p8 = (unsigned long long)pk
                            | ((unsigned long long)pk2 << 32);       // 4 cols
      if (isPub)
        __hip_atomic_store((unsigned long long*)ppub[rg], p8,
                           __ATOMIC_RELAXED, __HIP_MEMORY_SCOPE_AGENT);
    }
#pragma unroll
    for (int rg = 0; rg < 4; ++rg) ppub[rg] += H_SZ;

    // ---- write the prefetched x_{t+2} into buffer (t+2)%3 ----
    // (write end-of-t; read pre-barrier at t+2; barrier(t+1) separates ->
    //  race-free. Previous reader of this buffer finished pre-barrier(t-1).)
    if (havex){
      unsigned short* pp = xdst[(t + 2) % 3];
      pp[0] = f2bf(xv.x); pp[1] = f2bf(xv.y); pp[2] = f2bf(xv.z); pp[3] = f2bf(xv.w);
    }
    // no trailing barrier: next iteration uses the OTHER h parity buffer
  }
}

// ---------------- logits = hs @ Wd + bd ----------------
__global__ void k_logits(const unsigned short* __restrict__ hs,
                         const float* __restrict__ Wd, const float* __restrict__ bd,
                         float* __restrict__ out)
{
  __shared__ float wd_s[H_SZ*L_SZ];
  __shared__ float bd_s[L_SZ];
  for (int i = threadIdx.x; i < H_SZ*L_SZ; i += 128) wd_s[i] = Wd[i];
  if (threadIdx.x < L_SZ) bd_s[threadIdx.x] = bd[threadIdx.x];
  __syncthreads();

  long row = (long)blockIdx.x*128 + threadIdx.x;   // 0..32767
  const unsigned short* hp = hs + row*H_SZ;
  float acc[9];
#pragma unroll
  for (int jj = 0; jj < 9; ++jj) acc[jj] = 0.f;
  for (int k = 0; k < H_SZ; k += 8){
    uint4 v = *(const uint4*)(hp + k);
    const unsigned short* u = (const unsigned short*)&v;
#pragma unroll
    for (int l = 0; l < 8; ++l){
      float hf = bf2f(u[l]);
#pragma unroll
      for (int jj = 0; jj < 9; ++jj)
        acc[jj] = fmaf(hf, wd_s[(k + l)*L_SZ + jj], acc[jj]);
    }
  }
  float* op = out + row*L_SZ;
#pragma unroll
  for (int jj = 0; jj < 9; ++jj) op[jj] = acc[jj] + bd_s[jj];
}

// ---------------- CRF: score + forward algorithm ----------------
__global__ void k_crf(const float* __restrict__ logits, const int* __restrict__ labels,
                      const float* __restrict__ trans, const float* __restrict__ lensf,
                      float* __restrict__ out_ll)
{
  int b = blockIdx.x;
  int lane = threadIdx.x;             // 64 threads = 1 wave
  int len = (int)lensf[b];
  const float* lg  = logits + (long)b*T_SZ*L_SZ;
  const int*   lab = labels + b*T_SZ;

  float s = 0.f;
  for (int t = lane; t < T_SZ; t += 64){
    if (t < len){
      s += lg[t*L_SZ + lab[t]];
      if (t >= 1) s += trans[lab[t-1]*L_SZ + lab[t]];
    }
  }
  for (int off = 32; off; off >>= 1) s += __shfl_down(s, off, 64);

  float tr[9];
#pragma unroll
  for (int i = 0; i < 9; ++i) tr[i] = (lane < 9) ? trans[i*L_SZ + lane] : 0.f;
  float alpha = (lane < 9) ? lg[lane] : -1e30f;

  for (int t = 1; t < T_SZ; ++t){
    float tmp[9];
#pragma unroll
    for (int i = 0; i < 9; ++i){
      float ai = __shfl(alpha, i, 64);
      tmp[i] = ai + tr[i];
    }
    float m0 = fmaxf(fmaxf(tmp[0], tmp[1]), tmp[2]);
    float m1 = fmaxf(fmaxf(tmp[3], tmp[4]), tmp[5]);
    float m2 = fmaxf(fmaxf(tmp[6], tmp[7]), tmp[8]);
    float m  = fmaxf(fmaxf(m0, m1), m2);
    float e = 0.f;
#pragma unroll
    for (int i = 0; i < 9; ++i) e += __expf(tmp[i] - m);
    float lgv = (lane < 9) ? lg[t*L_SZ + lane] : 0.f;
    float nv = m + __logf(e) + lgv;
    if (t < len && lane < 9) alpha = nv;
  }

  float mm = (lane < 9) ? alpha : -1e30f;
  for (int off = 8; off; off >>= 1) mm = fmaxf(mm, __shfl_down(mm, off, 64));
  mm = __shfl(mm, 0, 64);
  float ee = (lane < 9) ? __expf(alpha - mm) : 0.f;
  for (int off = 8; off; off >>= 1) ee += __shfl_down(ee, off, 64);
  if (lane == 0) out_ll[b] = s - (mm + __logf(ee));
}

extern "C" void kernel_launch(void* const* d_in, const int* in_sizes, int n_in,
                              void* d_out, int out_size, void* d_ws, size_t ws_size,
                              hipStream_t stream)
{
  const int*   text   = (const int*)  d_in[0];
  const int*   labels = (const int*)  d_in[1];
  const float* embed  = (const float*)d_in[2];
  const float* Wx     = (const float*)d_in[3];
  const float* Wh     = (const float*)d_in[4];
  const float* bias   = (const float*)d_in[5];
  const float* Wd     = (const float*)d_in[6];
  const float* bd     = (const float*)d_in[7];
  const float* trans  = (const float*)d_in[8];

  float* out        = (float*)d_out;
  float* out_logits = out;
  float* out_lens   = out + LOGITS_N;
  float* out_ll     = out + LOGITS_N + B_SZ;

  unsigned short* hs = (unsigned short*)d_ws;

  k_reset <<<2048, 256, 0, stream>>>((unsigned long long*)hs);
  k_lens  <<<B_SZ, 256, 0, stream>>>(text, out_lens);
  k_lstm  <<<256, 256, 0, stream>>>(text, embed, Wx, Wh, bias, hs);
  k_logits<<<256, 128, 0, stream>>>(hs, Wd, bd, out_logits);
  k_crf   <<<B_SZ, 64, 0, stream>>>(out_logits, labels, trans, out_lens, out_ll);
}